// Round 5
// baseline (225.042 us; speedup 1.0000x reference)
//
#include <hip/hip_runtime.h>

#define B_     16
#define D_     256
#define HEADS_ 8
#define N_     32
#define H_     56
#define W_     56
#define L_     3136
#define LDB    40   // bf16 LDS row stride (80 B)

typedef short short8 __attribute__((ext_vector_type(8)));
typedef float f32x4  __attribute__((ext_vector_type(4)));

__device__ __forceinline__ unsigned short f2bf(float f) {
    union { float f; unsigned u; } c; c.f = f;
    unsigned u = c.u;
    u += 0x7fffu + ((u >> 16) & 1u);   // RNE
    return (unsigned short)(u >> 16);
}

// ---------------------------------------------------------------------------
// qk[b,h,c] = sum_n q[b,h,n] * Wk[h*32+n, c]  (fp32 accum, bf16 out)
// qkb is [b][16][256] with rows 8..15 zeroed (MFMA A-tile padding).
// ---------------------------------------------------------------------------
__global__ __launch_bounds__(256) void qk_kernel(
    const float* __restrict__ q, const float* __restrict__ Wk,
    unsigned short* __restrict__ qkb)
{
    const int h = blockIdx.x;      // 0..7
    const int b = blockIdx.y;      // 0..15
    const int c = threadIdx.x;     // 0..255
    float s = 0.f;
#pragma unroll
    for (int n = 0; n < 32; ++n)
        s = fmaf(q[b * D_ + h * 32 + n], Wk[(size_t)(h * 32 + n) * D_ + c], s);
    qkb[((size_t)b * 16 + h) * D_ + c]     = f2bf(s);
    qkb[((size_t)b * 16 + 8 + h) * D_ + c] = 0;
}

// ---------------------------------------------------------------------------
// Wv, Wproj fp32 -> bf16
// ---------------------------------------------------------------------------
__global__ __launch_bounds__(256) void convert_w_kernel(
    const float* __restrict__ w0, const float* __restrict__ w1,
    unsigned short* __restrict__ o0, unsigned short* __restrict__ o1)
{
    const float* src = blockIdx.y ? w1 : w0;
    unsigned short* dst = blockIdx.y ? o1 : o0;
    const int i = (blockIdx.x * 256 + threadIdx.x) * 4;
    float4 v = *(const float4*)(src + i);
    uint2 o;
    o.x = (unsigned)f2bf(v.x) | ((unsigned)f2bf(v.y) << 16);
    o.y = (unsigned)f2bf(v.z) | ((unsigned)f2bf(v.w) << 16);
    *(uint2*)(dst + i) = o;
}

// ---------------------------------------------------------------------------
// V projection + S.  BM=128 (fam = bx&1 picks d-half), BN=64, BK=32.
// x converted to bf16 once at staging; Bs double-buffered -> 1 barrier/kt;
// x and Wv frags software-prefetched across the barrier.
// S = qk . x via one extra MFMA per wave (ni=w), fam==0 only.
// ---------------------------------------------------------------------------
__global__ __launch_bounds__(256) void gemm_kv_mfma(
    const float* __restrict__ x, const unsigned short* __restrict__ Wvb,
    const unsigned short* __restrict__ qkb,
    unsigned short* __restrict__ Vo, float* __restrict__ S)
{
    __shared__ unsigned short Bs[2][64][LDB];   // 10.2 KB

    const int bb  = blockIdx.z;
    const int bx  = blockIdx.x;
    const int l0  = (bx >> 1) * 64;
    const int fam = bx & 1;
    const int d0  = fam * 128;
    const int t   = threadIdx.x;
    const int w    = t >> 6;
    const int lane = t & 63;
    const int col  = lane & 15;
    const int quad = lane >> 4;

    f32x4 accV[2][4];
    f32x4 accS = (f32x4){0.f, 0.f, 0.f, 0.f};
#pragma unroll
    for (int mi = 0; mi < 2; ++mi)
#pragma unroll
        for (int ni = 0; ni < 4; ++ni) accV[mi][ni] = (f32x4){0.f, 0.f, 0.f, 0.f};

    const int sc  = t >> 3;          // c-row 0..31
    const int sl8 = (t & 7) * 8;     // l offset
    const float* xrow = x + ((size_t)bb * D_ + sc) * L_ + l0 + sl8;
    const unsigned short* wv0 = Wvb + (size_t)(d0 + w * 32 + col) * D_ + quad * 8;
    const unsigned short* qk0 = qkb + ((size_t)bb * 16 + col) * D_ + quad * 8;

    // prefetch kt=0
    float4 xa = *(const float4*)xrow;
    float4 xb4 = *(const float4*)(xrow + 4);
    short8 av[2], aq;
    av[0] = *(const short8*)wv0;
    av[1] = *(const short8*)(wv0 + 16 * D_);
    aq    = *(const short8*)qk0;

    for (int kt = 0; kt < 8; ++kt) {
        const int buf = kt & 1;
        // stage current chunk as bf16
        unsigned short hb[8];
        hb[0] = f2bf(xa.x);  hb[1] = f2bf(xa.y);
        hb[2] = f2bf(xa.z);  hb[3] = f2bf(xa.w);
        hb[4] = f2bf(xb4.x); hb[5] = f2bf(xb4.y);
        hb[6] = f2bf(xb4.z); hb[7] = f2bf(xb4.w);
#pragma unroll
        for (int i = 0; i < 8; ++i) Bs[buf][sl8 + i][sc] = hb[i];
        __syncthreads();

        // prefetch next chunk
        float4 xan, xbn; short8 avn[2], aqn;
        if (kt < 7) {
            const float* xp = xrow + (size_t)(kt + 1) * 32 * L_;
            xan = *(const float4*)xp;
            xbn = *(const float4*)(xp + 4);
            avn[0] = *(const short8*)(wv0 + (kt + 1) * 32);
            avn[1] = *(const short8*)(wv0 + 16 * D_ + (kt + 1) * 32);
            aqn    = *(const short8*)(qk0 + (kt + 1) * 32);
        }

        short8 bfr[4];
#pragma unroll
        for (int ni = 0; ni < 4; ++ni)
            bfr[ni] = *(const short8*)&Bs[buf][ni * 16 + col][quad * 8];

#pragma unroll
        for (int mi = 0; mi < 2; ++mi)
#pragma unroll
            for (int ni = 0; ni < 4; ++ni)
                accV[mi][ni] = __builtin_amdgcn_mfma_f32_16x16x32_bf16(
                    av[mi], bfr[ni], accV[mi][ni], 0, 0, 0);
        if (fam == 0)
            accS = __builtin_amdgcn_mfma_f32_16x16x32_bf16(aq, bfr[w], accS, 0, 0, 0);

        xa = xan; xb4 = xbn; av[0] = avn[0]; av[1] = avn[1]; aq = aqn;
    }

    // ---- V epilogue: Vo[(bh*L + l)*32 + (d&31)] ----
    const int hh = fam * 4 + w;
#pragma unroll
    for (int mi = 0; mi < 2; ++mi) {
        const int dn = mi * 16 + quad * 4;
#pragma unroll
        for (int ni = 0; ni < 4; ++ni) {
            unsigned short pk[4];
#pragma unroll
            for (int r = 0; r < 4; ++r) pk[r] = f2bf(accV[mi][ni][r]);
            const int l = l0 + ni * 16 + col;
            *(uint2*)(Vo + ((((size_t)(bb * HEADS_ + hh)) * L_ + l) << 5) + dn) =
                *(const uint2*)pk;
        }
    }

    // ---- S epilogue (fam 0): wave w holds ni=w; rows 0..7 are heads ----
    if (fam == 0 && quad < 2) {
        const int l = l0 + w * 16 + col;
#pragma unroll
        for (int r = 0; r < 4; ++r) {
            const int h = quad * 4 + r;
            S[(size_t)(bb * HEADS_ + h) * L_ + l] = accS[r];
        }
    }
}

// ---------------------------------------------------------------------------
// attend: LDS-staged. Block = (8-row band, 8-ch group, b*h).
// ---------------------------------------------------------------------------
__global__ __launch_bounds__(256) void attend_kernel(
    const float* __restrict__ S, const unsigned short* __restrict__ Vo,
    const float* __restrict__ pos_emb, const float* __restrict__ Wlin,
    unsigned short* __restrict__ Om)
{
    __shared__ unsigned short Vs[10][58][8];
    __shared__ float Ss[10][58];

    const int band = blockIdx.x;
    const int half = blockIdx.y;
    const int bh   = blockIdx.z;
    const int y0   = band * 8;
    const int t    = threadIdx.x;

    const float* Sb = S + (size_t)bh * L_;
    for (int j = t; j < 580; j += 256) {
        const int row = j / 58, c = j - row * 58;
        const int gr = y0 - 1 + row, gc = c - 1;
        const bool in = (gr >= 0 && gr < H_ && gc >= 0 && gc < W_);
        Ss[row][c] = in ? Sb[gr * W_ + gc] : 0.f;
        uint4 vv = make_uint4(0u, 0u, 0u, 0u);
        if (in)
            vv = *(const uint4*)(Vo + (((size_t)bh * L_ + gr * W_ + gc) << 5) + half * 8);
        *(uint4*)&Vs[row][c][0] = vv;
    }
    __syncthreads();

    const float scale = Wlin[0] + Wlin[1] + Wlin[2] + Wlin[3];
    const float pe0 = pos_emb[0], pe1 = pos_emb[1], pe2 = pos_emb[2];
    const float pe3 = pos_emb[3], pe4 = pos_emb[4];
    const float bias[9] = {pe0, pe1, pe2, pe1, pe2, pe3, pe2, pe3, pe4};

    for (int p = t; p < 448; p += 256) {
        const int yl = p / 56, xx = p - yl * 56;
        const int lr = yl + 1, lc = xx + 1;

        float lg[9], m = -1e30f;
#pragma unroll
        for (int dy = 0; dy < 3; ++dy)
#pragma unroll
            for (int dx = 0; dx < 3; ++dx) {
                const int k = dy * 3 + dx;
                lg[k] = Ss[lr - 1 + dy][lc - 1 + dx] + bias[k];
                m = fmaxf(m, lg[k]);
            }
        float ssum = 0.f;
#pragma unroll
        for (int k = 0; k < 9; ++k) { lg[k] = __expf(lg[k] - m); ssum += lg[k]; }
        const float inv = scale / ssum;

        float om[8] = {0.f, 0.f, 0.f, 0.f, 0.f, 0.f, 0.f, 0.f};
#pragma unroll
        for (int dy = 0; dy < 3; ++dy)
#pragma unroll
            for (int dx = 0; dx < 3; ++dx) {
                const float wk = lg[dy * 3 + dx] * inv;
                const uint4 v = *(const uint4*)&Vs[lr - 1 + dy][lc - 1 + dx][0];
                const unsigned* u = (const unsigned*)&v;
#pragma unroll
                for (int i = 0; i < 4; ++i) {
                    union { unsigned uu; float f; } lo, hi;
                    lo.uu = u[i] << 16;
                    hi.uu = u[i] & 0xffff0000u;
                    om[2 * i]     = fmaf(wk, lo.f, om[2 * i]);
                    om[2 * i + 1] = fmaf(wk, hi.f, om[2 * i + 1]);
                }
            }

        unsigned short ob[8];
#pragma unroll
        for (int i = 0; i < 8; ++i) ob[i] = f2bf(om[i]);
        const int l = (y0 + yl) * W_ + xx;
        *(uint4*)(Om + (((size_t)bh * L_ + l) << 5) + half * 8) = *(const uint4*)ob;
    }
}

// ---------------------------------------------------------------------------
// out = Wproj @ Om.  BM=128 (fam), BN=64; Om staged (uint4/thread),
// double-buffered, A-frags prefetched from global (L2-hot).
// ---------------------------------------------------------------------------
__global__ __launch_bounds__(256) void gemm_proj_mfma(
    const unsigned short* __restrict__ Om, const unsigned short* __restrict__ Wpb,
    float* __restrict__ Out)
{
    __shared__ unsigned short Bs[2][64][LDB];

    const int bb  = blockIdx.z;
    const int bx  = blockIdx.x;
    const int l0  = (bx >> 1) * 64;
    const int fam = bx & 1;
    const int d0  = fam * 128;
    const int t   = threadIdx.x;
    const int w    = t >> 6;
    const int lane = t & 63;
    const int col  = lane & 15;
    const int quad = lane >> 4;

    f32x4 acc[2][4];
#pragma unroll
    for (int mi = 0; mi < 2; ++mi)
#pragma unroll
        for (int ni = 0; ni < 4; ++ni) acc[mi][ni] = (f32x4){0.f, 0.f, 0.f, 0.f};

    const int srow = t >> 2;
    const int skc  = (t & 3) * 8;
    const unsigned short* omr = Om + (((size_t)bb * HEADS_ * L_ + l0 + srow) << 5) + skc;
    const unsigned short* wp0 = Wpb + (size_t)(d0 + w * 32 + col) * D_ + quad * 8;

    uint4 bg = *(const uint4*)omr;
    short8 a[2];
    a[0] = *(const short8*)wp0;
    a[1] = *(const short8*)(wp0 + 16 * D_);

    for (int kt = 0; kt < 8; ++kt) {
        const int buf = kt & 1;
        *(uint4*)&Bs[buf][srow][skc] = bg;
        __syncthreads();

        uint4 bgn; short8 an[2];
        if (kt < 7) {
            bgn = *(const uint4*)(omr + (((size_t)(kt + 1)) * L_ << 5));
            an[0] = *(const short8*)(wp0 + (kt + 1) * 32);
            an[1] = *(const short8*)(wp0 + 16 * D_ + (kt + 1) * 32);
        }

        short8 bfr[4];
#pragma unroll
        for (int ni = 0; ni < 4; ++ni)
            bfr[ni] = *(const short8*)&Bs[buf][ni * 16 + col][quad * 8];

#pragma unroll
        for (int mi = 0; mi < 2; ++mi)
#pragma unroll
            for (int ni = 0; ni < 4; ++ni)
                acc[mi][ni] = __builtin_amdgcn_mfma_f32_16x16x32_bf16(
                    a[mi], bfr[ni], acc[mi][ni], 0, 0, 0);

        bg = bgn; a[0] = an[0]; a[1] = an[1];
    }

#pragma unroll
    for (int mi = 0; mi < 2; ++mi)
#pragma unroll
        for (int ni = 0; ni < 4; ++ni)
#pragma unroll
            for (int r = 0; r < 4; ++r) {
                const int d = d0 + w * 32 + mi * 16 + quad * 4 + r;
                const int l = l0 + ni * 16 + col;
                Out[((size_t)bb * D_ + d) * L_ + l] = acc[mi][ni][r];
            }
}

// ---------------------------------------------------------------------------
extern "C" void kernel_launch(void* const* d_in, const int* in_sizes, int n_in,
                              void* d_out, int out_size, void* d_ws, size_t ws_size,
                              hipStream_t stream)
{
    const float* x       = (const float*)d_in[0];
    const float* q       = (const float*)d_in[1];
    const float* Wk      = (const float*)d_in[2];
    const float* Wv      = (const float*)d_in[3];
    const float* pos_emb = (const float*)d_in[4];
    const float* Wlin    = (const float*)d_in[5];
    const float* Wproj   = (const float*)d_in[6];
    float* out = (float*)d_out;

    const size_t planeE = (size_t)B_ * D_ * L_;
    unsigned short* Vo  = (unsigned short*)d_ws;
    unsigned short* Om  = Vo + planeE;
    unsigned short* Wvb = Om + planeE;
    unsigned short* Wpb = Wvb + D_ * D_;
    unsigned short* qkb = Wpb + D_ * D_;          // 16*16*256
    float*          S   = (float*)(qkb + B_ * 16 * D_);

    qk_kernel<<<dim3(HEADS_, B_), 256, 0, stream>>>(q, Wk, qkb);
    convert_w_kernel<<<dim3(64, 2), 256, 0, stream>>>(Wv, Wproj, Wvb, Wpb);
    gemm_kv_mfma<<<dim3(2 * (L_ / 64), 1, B_), 256, 0, stream>>>(x, Wvb, qkb, Vo, S);
    attend_kernel<<<dim3(7, 4, B_ * HEADS_), 256, 0, stream>>>(
        S, Vo, pos_emb, Wlin, Om);
    gemm_proj_mfma<<<dim3(2 * (L_ / 64), 1, B_), 256, 0, stream>>>(Om, Wpb, out);
}